// Round 1
// baseline (145.439 us; speedup 1.0000x reference)
//
#include <hip/hip_runtime.h>

#define IMG_H 512
#define IMG_W 512
#define N_IMG 32
#define ROWS  32                 // output rows per block band
#define LC    (IMG_W + 8)        // 520 load columns (halo 4 each side)
#define VIDX(c) ((c) + ((c) >> 5))
#define VSZ  (LC + (LC >> 5) + 1)   // 537, swizzled vsum row size
#define NPIX (32.0f * 512.0f * 512.0f)

__device__ __forceinline__ float cc_of(float sI, float sT, float sII, float sTT, float sIT) {
    const float inv81 = 1.0f / 81.0f;
    float cross = sIT - sI * sT * inv81;
    float tv    = sTT - sT * sT * inv81;
    float iv    = sII - sI * sI * inv81;
    return cross * cross / (tv * iv + 1e-5f);
}

__global__ __launch_bounds__(256, 2)
void cc_loss_kernel(const float* __restrict__ in, const float* __restrict__ tg,
                    float* __restrict__ out) {
    __shared__ float ringI[9][LC];
    __shared__ float ringT[9][LC];
    __shared__ float vs[5][VSZ];
    __shared__ float red[4];

    const int t    = threadIdx.x;
    const int b    = blockIdx.x >> 4;        // image index (16 bands per image)
    const int band = blockIdx.x & 15;
    const int r0   = band * ROWS;
    const size_t base = (size_t)b * (IMG_H * IMG_W);
    const float* ip = in + base;
    const float* tp = tg + base;

    // zero the 9-row ring (conceptual rows above the band are zero = padding)
    for (int i = t; i < 9 * LC; i += 256) {
        (&ringI[0][0])[i] = 0.0f;
        (&ringT[0][0])[i] = 0.0f;
    }
    __syncthreads();

    // vertical sliding sums (registers), per owned load-column
    float sI0=0,sT0=0,sII0=0,sTT0=0,sIT0=0;   // lc = t
    float sI1=0,sT1=0,sII1=0,sTT1=0,sIT1=0;   // lc = 256+t
    float sI2=0,sT2=0,sII2=0,sTT2=0,sIT2=0;   // lc = 512+t (t<8 only)

    float acc = 0.0f;

    for (int it = 0; it < ROWS + 8; ++it) {
        const int ir   = r0 - 4 + it;        // image row entering the window
        const int slot = it % 9;
        const bool rowok = (ir >= 0) && (ir < IMG_H);
        const float* iprow = ip + (size_t)ir * IMG_W;
        const float* tprow = tp + (size_t)ir * IMG_W;

        // ---- phase V: update vertical sums, publish to vs[] ----
        {   // owned column 0: lc = t, x = t-4
            const int lc = t, x = t - 4;
            const bool ok = rowok && (x >= 0);
            float I = ok ? iprow[x] : 0.0f;
            float T = ok ? (tprow[x] + 1.0f) * 0.5f : 0.0f;
            float Io = ringI[slot][lc], To = ringT[slot][lc];
            sI0  += I - Io;           sT0  += T - To;
            sII0 += I*I - Io*Io;      sTT0 += T*T - To*To;
            sIT0 += I*T - Io*To;
            ringI[slot][lc] = I;      ringT[slot][lc] = T;
            vs[0][VIDX(lc)] = sI0;  vs[1][VIDX(lc)] = sT0;  vs[2][VIDX(lc)] = sII0;
            vs[3][VIDX(lc)] = sTT0; vs[4][VIDX(lc)] = sIT0;
        }
        {   // owned column 1: lc = 256+t, x = 252+t (always in [0,512))
            const int lc = 256 + t, x = lc - 4;
            float I = rowok ? iprow[x] : 0.0f;
            float T = rowok ? (tprow[x] + 1.0f) * 0.5f : 0.0f;
            float Io = ringI[slot][lc], To = ringT[slot][lc];
            sI1  += I - Io;           sT1  += T - To;
            sII1 += I*I - Io*Io;      sTT1 += T*T - To*To;
            sIT1 += I*T - Io*To;
            ringI[slot][lc] = I;      ringT[slot][lc] = T;
            vs[0][VIDX(lc)] = sI1;  vs[1][VIDX(lc)] = sT1;  vs[2][VIDX(lc)] = sII1;
            vs[3][VIDX(lc)] = sTT1; vs[4][VIDX(lc)] = sIT1;
        }
        if (t < 8) {  // ragged tail: lc = 512+t, x = 508+t (valid only x<512)
            const int lc = 512 + t, x = lc - 4;
            const bool ok = rowok && (x < IMG_W);
            float I = ok ? iprow[x] : 0.0f;
            float T = ok ? (tprow[x] + 1.0f) * 0.5f : 0.0f;
            float Io = ringI[slot][lc], To = ringT[slot][lc];
            sI2  += I - Io;           sT2  += T - To;
            sII2 += I*I - Io*Io;      sTT2 += T*T - To*To;
            sIT2 += I*T - Io*To;
            ringI[slot][lc] = I;      ringT[slot][lc] = T;
            vs[0][VIDX(lc)] = sI2;  vs[1][VIDX(lc)] = sT2;  vs[2][VIDX(lc)] = sII2;
            vs[3][VIDX(lc)] = sTT2; vs[4][VIDX(lc)] = sIT2;
        }
        __syncthreads();

        // ---- phase H: horizontal 9-sums + cc for 2 pixels/thread ----
        if (it >= 8) {
            const int c0 = 2 * t;   // output cols c0, c0+1; need vs cols c0..c0+9
            float se[5], so[5];
            #pragma unroll
            for (int a = 0; a < 5; ++a) {
                float v[10];
                #pragma unroll
                for (int k = 0; k < 10; ++k) v[k] = vs[a][VIDX(c0 + k)];
                float s = ((v[0]+v[1]) + (v[2]+v[3])) + ((v[4]+v[5]) + (v[6]+v[7])) + v[8];
                se[a] = s;
                so[a] = s - v[0] + v[9];
            }
            acc += cc_of(se[0], se[1], se[2], se[3], se[4]);
            acc += cc_of(so[0], so[1], so[2], so[3], so[4]);
        }
        __syncthreads();   // protect vs[] before next row's phase V
    }

    // ---- block reduction ----
    #pragma unroll
    for (int off = 32; off > 0; off >>= 1) acc += __shfl_down(acc, off);
    const int wave = t >> 6, lane = t & 63;
    if (lane == 0) red[wave] = acc;
    __syncthreads();
    if (t == 0) {
        float s = red[0] + red[1] + red[2] + red[3];
        atomicAdd(out, s * (-1.0f / NPIX));
    }
}

extern "C" void kernel_launch(void* const* d_in, const int* in_sizes, int n_in,
                              void* d_out, int out_size, void* d_ws, size_t ws_size,
                              hipStream_t stream) {
    const float* in = (const float*)d_in[0];   // "input"
    const float* tg = (const float*)d_in[1];   // "target"
    float* out = (float*)d_out;

    hipMemsetAsync(out, 0, sizeof(float), stream);   // d_out is re-poisoned; atomic target must start at 0
    dim3 grid(N_IMG * (IMG_H / ROWS));               // 32 images * 16 bands = 512 blocks
    cc_loss_kernel<<<grid, 256, 0, stream>>>(in, tg, out);
}

// Round 2
// 142.683 us; speedup vs baseline: 1.0193x; 1.0193x over previous
//
#include <hip/hip_runtime.h>

#define IMG_H 512
#define IMG_W 512
#define N_IMG 32
#define ROWS  16                  // output rows per block band
#define BANDS (IMG_H / ROWS)      // 32 bands per image
#define ITERS (ROWS + 8)          // 24 row-iterations per block
#define SW(c) ((c) + 2 * ((c) >> 5))   // even swizzle: keeps float2 alignment, spreads banks
#define VSZ   552                 // SW(519)=551, +1
#define NPIX  (32.0f * 512.0f * 512.0f)

__device__ __forceinline__ float cc_of(float sI, float sT, float sII, float sTT, float sIT) {
    const float inv81 = 1.0f / 81.0f;
    float cross = sIT - sI * sT * inv81;
    float tv    = sTT - sT * sT * inv81;
    float iv    = sII - sI * sI * inv81;
    return cross * cross / (tv * iv + 1e-5f);
}

__global__ __launch_bounds__(256, 4)
void cc_loss_kernel(const float* __restrict__ in, const float* __restrict__ tg,
                    float* __restrict__ out) {
    // double-buffered vertical-sum rows; no ring (trailing row re-loaded from L2)
    __shared__ __align__(16) float vs[2][5][VSZ];
    __shared__ float red[4];

    const int t    = threadIdx.x;
    const int b    = blockIdx.x >> 5;        // image
    const int band = blockIdx.x & 31;
    const int r0   = band * ROWS;
    const size_t base = (size_t)b * (IMG_H * IMG_W);
    const float* ip = in + base;
    const float* tp = tg + base;

    // owned load-columns: lc = t (x=t-4), lc = 256+t (x=252+t), lc = 512+t for t<8 (x=508+t)
    const int x0 = t - 4;
    const int x1 = 252 + t;
    const int x2 = 508 + t;
    const bool c0ok  = (x0 >= 0);
    const bool c2own = (t < 8);
    const bool c2ok  = c2own && (x2 < IMG_W);   // only t<4 has a real pixel

    float sI0=0,sT0=0,sII0=0,sTT0=0,sIT0=0;
    float sI1=0,sT1=0,sII1=0,sTT1=0,sIT1=0;
    float sI2=0,sT2=0,sII2=0,sTT2=0,sIT2=0;
    float acc = 0.0f;

    // prefetch registers: leading row (p*) and trailing row (q*)
    float pI0,pT0,pI1,pT1,pI2,pT2;
    float qI0,qT0,qI1,qT1,qI2,qT2;

    {   // preload leading row for it=0 (ir = r0-4); trailing is zero (window growing)
        const int ir = r0 - 4;
        const bool rk = (ir >= 0);
        const float* irow = ip + (ptrdiff_t)ir * IMG_W;
        const float* trow = tp + (ptrdiff_t)ir * IMG_W;
        pI0 = (rk && c0ok) ? irow[x0] : 0.0f;
        pT0 = (rk && c0ok) ? (trow[x0] + 1.0f) * 0.5f : 0.0f;
        pI1 = rk ? irow[x1] : 0.0f;
        pT1 = rk ? (trow[x1] + 1.0f) * 0.5f : 0.0f;
        pI2 = (rk && c2ok) ? irow[x2] : 0.0f;
        pT2 = (rk && c2ok) ? (trow[x2] + 1.0f) * 0.5f : 0.0f;
        qI0=qT0=qI1=qT1=qI2=qT2=0.0f;
    }

    for (int it = 0; it < ITERS; ++it) {
        const int buf = it & 1;

        // ---- V phase: slide vertical sums with prefetched rows, publish ----
        sI0  += pI0 - qI0;            sT0  += pT0 - qT0;
        sII0 += pI0*pI0 - qI0*qI0;    sTT0 += pT0*pT0 - qT0*qT0;
        sIT0 += pI0*pT0 - qI0*qT0;
        sI1  += pI1 - qI1;            sT1  += pT1 - qT1;
        sII1 += pI1*pI1 - qI1*qI1;    sTT1 += pT1*pT1 - qT1*qT1;
        sIT1 += pI1*pT1 - qI1*qT1;

        {
            const int i0 = SW(t), i1 = SW(256 + t);
            vs[buf][0][i0] = sI0;   vs[buf][1][i0] = sT0;   vs[buf][2][i0] = sII0;
            vs[buf][3][i0] = sTT0;  vs[buf][4][i0] = sIT0;
            vs[buf][0][i1] = sI1;   vs[buf][1][i1] = sT1;   vs[buf][2][i1] = sII1;
            vs[buf][3][i1] = sTT1;  vs[buf][4][i1] = sIT1;
        }
        if (c2own) {
            sI2  += pI2 - qI2;            sT2  += pT2 - qT2;
            sII2 += pI2*pI2 - qI2*qI2;    sTT2 += pT2*pT2 - qT2*qT2;
            sIT2 += pI2*pT2 - qI2*qT2;
            const int i2 = SW(512 + t);
            vs[buf][0][i2] = sI2;   vs[buf][1][i2] = sT2;   vs[buf][2][i2] = sII2;
            vs[buf][3][i2] = sTT2;  vs[buf][4][i2] = sIT2;
        }

        // ---- prefetch rows for iteration it+1 (hidden behind barrier + H) ----
        {
            const int irn = r0 - 3 + it;                 // next leading row
            const bool rkn = (irn >= 0) && (irn < IMG_H);
            const float* irow = ip + (ptrdiff_t)irn * IMG_W;
            const float* trow = tp + (ptrdiff_t)irn * IMG_W;
            pI0 = (rkn && c0ok) ? irow[x0] : 0.0f;
            pT0 = (rkn && c0ok) ? (trow[x0] + 1.0f) * 0.5f : 0.0f;
            pI1 = rkn ? irow[x1] : 0.0f;
            pT1 = rkn ? (trow[x1] + 1.0f) * 0.5f : 0.0f;
            pI2 = (rkn && c2ok) ? irow[x2] : 0.0f;
            pT2 = (rkn && c2ok) ? (trow[x2] + 1.0f) * 0.5f : 0.0f;

            const int irm = irn - 9;                     // next trailing row
            const bool sk = ((it + 1) >= 9) && (irm >= 0);   // irm < IMG_H guaranteed
            const float* jrow = ip + (ptrdiff_t)irm * IMG_W;
            const float* urow = tp + (ptrdiff_t)irm * IMG_W;
            qI0 = (sk && c0ok) ? jrow[x0] : 0.0f;
            qT0 = (sk && c0ok) ? (urow[x0] + 1.0f) * 0.5f : 0.0f;
            qI1 = sk ? jrow[x1] : 0.0f;
            qT1 = sk ? (urow[x1] + 1.0f) * 0.5f : 0.0f;
            qI2 = (sk && c2ok) ? jrow[x2] : 0.0f;
            qT2 = (sk && c2ok) ? (urow[x2] + 1.0f) * 0.5f : 0.0f;
        }

        __syncthreads();

        // ---- H phase: 9-wide horizontal sums via aligned float2, 2 px/thread ----
        if (it >= 8) {
            const int c0 = 2 * t;
            float se[5], so[5];
            #pragma unroll
            for (int a = 0; a < 5; ++a) {
                const float* row = vs[buf][a];
                float2 v0 = *(const float2*)&row[SW(c0 + 0)];
                float2 v1 = *(const float2*)&row[SW(c0 + 2)];
                float2 v2 = *(const float2*)&row[SW(c0 + 4)];
                float2 v3 = *(const float2*)&row[SW(c0 + 6)];
                float2 v4 = *(const float2*)&row[SW(c0 + 8)];
                float s = ((v0.x + v0.y) + (v1.x + v1.y)) +
                          ((v2.x + v2.y) + (v3.x + v3.y)) + v4.x;
                se[a] = s;
                so[a] = s - v0.x + v4.y;
            }
            acc += cc_of(se[0], se[1], se[2], se[3], se[4]);
            acc += cc_of(so[0], so[1], so[2], so[3], so[4]);
        }
        // no second barrier: next iteration writes the other buffer; reuse of this
        // buffer happens only after the next iteration's barrier.
    }

    // ---- block reduction ----
    #pragma unroll
    for (int off = 32; off > 0; off >>= 1) acc += __shfl_down(acc, off);
    const int wave = t >> 6, lane = t & 63;
    if (lane == 0) red[wave] = acc;
    __syncthreads();
    if (t == 0) {
        float s = red[0] + red[1] + red[2] + red[3];
        atomicAdd(out, s * (-1.0f / NPIX));
    }
}

extern "C" void kernel_launch(void* const* d_in, const int* in_sizes, int n_in,
                              void* d_out, int out_size, void* d_ws, size_t ws_size,
                              hipStream_t stream) {
    const float* in = (const float*)d_in[0];
    const float* tg = (const float*)d_in[1];
    float* out = (float*)d_out;

    hipMemsetAsync(out, 0, sizeof(float), stream);
    dim3 grid(N_IMG * BANDS);                 // 32 * 32 = 1024 blocks
    cc_loss_kernel<<<grid, 256, 0, stream>>>(in, tg, out);
}

// Round 3
// 126.320 us; speedup vs baseline: 1.1514x; 1.1295x over previous
//
#include <hip/hip_runtime.h>

#define IMG_H 512
#define IMG_W 512
#define N_IMG 32
#define ROWS  16
#define BANDS (IMG_H / ROWS)      // 32 bands/image
#define STEPS 12                  // 2 rows per step: 24 row-slides per band
#define VROW  528                 // padded LDS row (cols 0..519 used), keeps float4 alignment
#define NPIX  (32.0f * 512.0f * 512.0f)

struct RowVals { float2 mI, mT, tI, tT; };   // main pair (cols 2t,2t+1), tail pair (cols 512+2t.., t<4)
struct Sums    { float2 I, T, II, TT, IT; };

__device__ __forceinline__ RowVals load_row(const float* __restrict__ ip,
                                            const float* __restrict__ tp,
                                            int r, int t) {
    RowVals v;
    v.mI = make_float2(0.f, 0.f); v.mT = v.mI; v.tI = v.mI; v.tT = v.mI;
    if (r >= 0 && r < IMG_H) {
        const float* irow = ip + (ptrdiff_t)r * IMG_W;
        const float* trow = tp + (ptrdiff_t)r * IMG_W;
        if (t >= 2) {                       // load-cols 2t,2t+1 -> img cols 2t-4,2t-3 (in range)
            v.mI = *(const float2*)(irow + 2 * t - 4);
            float2 a = *(const float2*)(trow + 2 * t - 4);
            v.mT = make_float2((a.x + 1.f) * 0.5f, (a.y + 1.f) * 0.5f);
        } else {                            // t=0,1: main cols are left-pad; load tail cols 508..511
            v.tI = *(const float2*)(irow + 508 + 2 * t);
            float2 a = *(const float2*)(trow + 508 + 2 * t);
            v.tT = make_float2((a.x + 1.f) * 0.5f, (a.y + 1.f) * 0.5f);
        }
    }
    return v;
}

__device__ __forceinline__ void slide(Sums& s, float2 pI, float2 pT, float2 qI, float2 qT) {
    s.I.x  += pI.x - qI.x;            s.I.y  += pI.y - qI.y;
    s.T.x  += pT.x - qT.x;            s.T.y  += pT.y - qT.y;
    s.II.x += pI.x*pI.x - qI.x*qI.x;  s.II.y += pI.y*pI.y - qI.y*qI.y;
    s.TT.x += pT.x*pT.x - qT.x*qT.x;  s.TT.y += pT.y*pT.y - qT.y*qT.y;
    s.IT.x += pI.x*pT.x - qI.x*qT.x;  s.IT.y += pI.y*pT.y - qI.y*qT.y;
}

__device__ __forceinline__ void publish(float* vb, int col, const Sums& s) {
    *(float2*)(vb + 0 * VROW + col) = s.I;
    *(float2*)(vb + 1 * VROW + col) = s.T;
    *(float2*)(vb + 2 * VROW + col) = s.II;
    *(float2*)(vb + 3 * VROW + col) = s.TT;
    *(float2*)(vb + 4 * VROW + col) = s.IT;
}

__device__ __forceinline__ float cc_of(float sI, float sT, float sII, float sTT, float sIT) {
    const float inv81 = 1.0f / 81.0f;
    float u     = sI * inv81;
    float w     = sT * inv81;
    float cross = fmaf(-u, sT, sIT);
    float iv    = fmaf(-u, sI, sII);
    float tv    = fmaf(-w, sT, sTT);
    float den   = fmaf(tv, iv, 1e-5f);
    return cross * cross * __builtin_amdgcn_rcpf(den);   // 1-ulp rcp: ample for 2.5e-4 threshold
}

__global__ __launch_bounds__(256, 4)
void cc_loss_kernel(const float* __restrict__ in, const float* __restrict__ tg,
                    float* __restrict__ out) {
    __shared__ __align__(16) float vs[2][5][VROW];   // [row A/B][array][col] = 21.1 KB
    __shared__ float red[4];

    const int t    = threadIdx.x;
    const int b    = blockIdx.x >> 5;
    const int band = blockIdx.x & 31;
    const int r0   = band * ROWS;
    const size_t base = (size_t)b * (IMG_H * IMG_W);
    const float* ip = in + base;
    const float* tp = tg + base;

    Sums mn = {}, tl = {};
    float acc = 0.0f;

    RowVals pA = load_row(ip, tp, r0 - 4, t);
    RowVals pB = load_row(ip, tp, r0 - 3, t);
    RowVals qA = {}, qB = {};

    for (int s = 0; s < STEPS; ++s) {
        // ---- V phase: slide 2 rows, publish v-sums (only when H will read them) ----
        slide(mn, pA.mI, pA.mT, qA.mI, qA.mT);
        if (t < 4) slide(tl, pA.tI, pA.tT, qA.tI, qA.tT);
        if (s >= 4) {
            publish(&vs[0][0][0], 2 * t, mn);
            if (t < 4) publish(&vs[0][0][0], 512 + 2 * t, tl);
        }
        slide(mn, pB.mI, pB.mT, qB.mI, qB.mT);
        if (t < 4) slide(tl, pB.tI, pB.tT, qB.tI, qB.tT);
        if (s >= 4) {
            publish(&vs[1][0][0], 2 * t, mn);
            if (t < 4) publish(&vs[1][0][0], 512 + 2 * t, tl);
        }

        // ---- prefetch rows for step s+1 (overlaps barrier + H phase) ----
        if (s + 1 < STEPS) {
            const int rA2 = r0 - 4 + 2 * (s + 1);
            const int rB2 = rA2 + 1;
            pA = load_row(ip, tp, rA2, t);
            pB = load_row(ip, tp, rB2, t);
            const int rqA = rA2 - 9, rqB = rB2 - 9;
            qA = load_row(ip, tp, (rqA >= r0 - 4) ? rqA : -1, t);
            qB = load_row(ip, tp, (rqB >= r0 - 4) ? rqB : -1, t);
        }

        // ---- H phase: 2 output rows, 4 px/thread, float4 LDS reads ----
        if (s >= 4) {
            __syncthreads();
            const int u = t & 127;                     // 128 threads per row
            const float* vb = &vs[t >> 7][0][0] + 4 * u;
            float h[5][4];
            #pragma unroll
            for (int a = 0; a < 5; ++a) {
                const float* rp = vb + a * VROW;       // load-cols 4u .. 4u+11
                float4 w0 = *(const float4*)(rp);
                float4 w1 = *(const float4*)(rp + 4);
                float4 w2 = *(const float4*)(rp + 8);
                float s0 = ((w0.x + w0.y) + (w0.z + w0.w)) +
                           ((w1.x + w1.y) + (w1.z + w1.w)) + w2.x;
                float s1 = s0 - w0.x + w2.y;
                float s2 = s1 - w0.y + w2.z;
                float s3 = s2 - w0.z + w2.w;
                h[a][0] = s0; h[a][1] = s1; h[a][2] = s2; h[a][3] = s3;
            }
            #pragma unroll
            for (int j = 0; j < 4; ++j)
                acc += cc_of(h[0][j], h[1][j], h[2][j], h[3][j], h[4][j]);
            __syncthreads();                           // protect vs before next publish
        }
    }

    // ---- block reduction ----
    #pragma unroll
    for (int off = 32; off > 0; off >>= 1) acc += __shfl_down(acc, off);
    const int wave = t >> 6, lane = t & 63;
    if (lane == 0) red[wave] = acc;
    __syncthreads();
    if (t == 0) {
        atomicAdd(out, (red[0] + red[1] + red[2] + red[3]) * (-1.0f / NPIX));
    }
}

extern "C" void kernel_launch(void* const* d_in, const int* in_sizes, int n_in,
                              void* d_out, int out_size, void* d_ws, size_t ws_size,
                              hipStream_t stream) {
    const float* in = (const float*)d_in[0];
    const float* tg = (const float*)d_in[1];
    float* out = (float*)d_out;

    hipMemsetAsync(out, 0, sizeof(float), stream);
    dim3 grid(N_IMG * BANDS);                 // 1024 blocks
    cc_loss_kernel<<<grid, 256, 0, stream>>>(in, tg, out);
}